// Round 4
// baseline (113718.958 us; speedup 1.0000x reference)
//
#include <hip/hip_runtime.h>
#include <hip/hip_bf16.h>
#include <hip/hip_cooperative_groups.h>

namespace cg = cooperative_groups;

constexpr int   NROWS = 65536;
constexpr int   NK    = 1024;
constexpr float PAv   = 1.0f / 65536.0f;
constexpr float PBv   = 1.0f / 1024.0f;
constexpr float FI    = 1.0f / 1.1f;          // GAMMA/(GAMMA+eps)
constexpr float NEG_INV_EPS = -10.0f;         // -1/eps
constexpr float STOPERR2 = 1e-12f;            // (1e-6)^2 on squared 2-norm
constexpr int   MAXIT = 1000;

// ---------------- Q conversion: P f32 -> Q bf16 ----------------
__device__ __forceinline__ unsigned int bfpack2(float lo, float hi) {
  return (unsigned int)__bfloat16_as_ushort(__float2bfloat16(lo)) |
         ((unsigned int)__bfloat16_as_ushort(__float2bfloat16(hi)) << 16);
}

__global__ __launch_bounds__(256)
void q_conv_kernel(const float* __restrict__ P, uint4* __restrict__ Qb)
{
  const size_t total8 = (size_t)NROWS * NK / 8;
  for (size_t i = (size_t)blockIdx.x * blockDim.x + threadIdx.x; i < total8;
       i += (size_t)gridDim.x * blockDim.x) {
    const float4* p4 = reinterpret_cast<const float4*>(P) + 2 * i;
    float4 a = p4[0], b = p4[1];
    uint4 o;
    o.x = bfpack2(__expf(a.x * NEG_INV_EPS), __expf(a.y * NEG_INV_EPS));
    o.y = bfpack2(__expf(a.z * NEG_INV_EPS), __expf(a.w * NEG_INV_EPS));
    o.z = bfpack2(__expf(b.x * NEG_INV_EPS), __expf(b.y * NEG_INV_EPS));
    o.w = bfpack2(__expf(b.z * NEG_INV_EPS), __expf(b.w * NEG_INV_EPS));
    Qb[i] = o;
  }
}

__device__ __forceinline__ void bf8_unpack(uint4 v, float* __restrict__ q) {
  q[0] = __uint_as_float(v.x << 16); q[1] = __uint_as_float(v.x & 0xffff0000u);
  q[2] = __uint_as_float(v.y << 16); q[3] = __uint_as_float(v.y & 0xffff0000u);
  q[4] = __uint_as_float(v.z << 16); q[5] = __uint_as_float(v.z & 0xffff0000u);
  q[6] = __uint_as_float(v.w << 16); q[7] = __uint_as_float(v.w & 0xffff0000u);
}

// ---------------- cooperative Sinkhorn iteration ----------------
// PROVEN geometry (round 1): 256 blocks x 1024 threads = 1 block/CU.
// Cooperative launch with 2 blocks/CU was REJECTED (rounds 2/3) -> keep 256.
constexpr int IT_BLOCKS  = 256;
constexpr int IT_THREADS = 1024;
constexpr int IT_WAVES   = IT_THREADS / 64;                 // 16
constexpr int IT_RPW     = NROWS / (IT_BLOCKS * IT_WAVES);  // 16 rows per wave

template<bool BF16>
__global__ __launch_bounds__(IT_THREADS, 4)
void ssk_iter(const void* __restrict__ src, float* __restrict__ cs_ring,
              float* __restrict__ b_out)
{
  cg::grid_group grid = cg::this_grid();
  __shared__ float b_lds[NK];
  __shared__ float wave_cs[IT_WAVES][NK];   // 64 KiB
  __shared__ float redsh[IT_WAVES];
  __shared__ float err_sh;

  const int tid  = threadIdx.x;
  const int wave = tid >> 6;
  const int lane = tid & 63;
  const int row0 = (blockIdx.x * IT_WAVES + wave) * IT_RPW;

  b_lds[tid] = PBv;                         // b0 = 1/K
  __syncthreads();

  int it = 0;
  for (;;) {
    float* __restrict__ cs_cur = cs_ring + (size_t)(it & 3) * NK;
    // zero the buffer used 2 iters ahead; its last readers/writers (iter it-2)
    // finished before SYNC(it-1), which every block has passed. Concurrent
    // redundant zero-writes store the same value: benign.
    cs_ring[(size_t)((it + 2) & 3) * NK + tid] = 0.0f;

    // lane's 16 columns (layout differs per path; consistent load/scatter)
    float bb[16];
    if constexpr (BF16) {
      #pragma unroll
      for (int j = 0; j < 8; ++j) {
        bb[j]     = b_lds[8 * lane + j];
        bb[8 + j] = b_lds[512 + 8 * lane + j];
      }
    } else {
      #pragma unroll
      for (int k = 0; k < 4; ++k)
        #pragma unroll
        for (int j = 0; j < 4; ++j)
          bb[4 * k + j] = b_lds[256 * k + 4 * lane + j];
    }
    float acc[16];
    #pragma unroll
    for (int t = 0; t < 16; ++t) acc[t] = 0.0f;

    for (int r = 0; r < IT_RPW; r += 4) {   // 4-row load batch: 8-16 loads in flight
      if constexpr (BF16) {
        const uint4* rp = reinterpret_cast<const uint4*>(src) + (size_t)(row0 + r) * (NK / 8);
        uint4 u[4][2];
        #pragma unroll
        for (int rr = 0; rr < 4; ++rr) {
          u[rr][0] = rp[rr * (NK / 8) + lane];
          u[rr][1] = rp[rr * (NK / 8) + 64 + lane];
        }
        #pragma unroll
        for (int pp = 0; pp < 2; ++pp) {            // rows in pairs: dual chains
          float qA[16], qB[16];
          bf8_unpack(u[2*pp][0], qA);   bf8_unpack(u[2*pp][1], qA + 8);
          bf8_unpack(u[2*pp+1][0], qB); bf8_unpack(u[2*pp+1][1], qB + 8);
          float dA = 0.f, dB = 0.f;
          #pragma unroll
          for (int t = 0; t < 16; ++t) {
            dA = fmaf(qA[t], bb[t], dA);
            dB = fmaf(qB[t], bb[t], dB);
          }
          #pragma unroll
          for (int off = 32; off; off >>= 1) {
            dA += __shfl_xor(dA, off);
            dB += __shfl_xor(dB, off);
          }
          const float aA = PAv / fmaxf(dA, 1e-12f);
          const float aB = PAv / fmaxf(dB, 1e-12f);
          #pragma unroll
          for (int t = 0; t < 16; ++t) {
            acc[t] = fmaf(aA, qA[t], acc[t]);
            acc[t] = fmaf(aB, qB[t], acc[t]);
          }
        }
      } else {
        const float4* rp = reinterpret_cast<const float4*>(src) + (size_t)(row0 + r) * (NK / 4);
        float4 v[4][4];
        #pragma unroll
        for (int rr = 0; rr < 4; ++rr)
          #pragma unroll
          for (int k = 0; k < 4; ++k)
            v[rr][k] = rp[rr * (NK / 4) + (k << 6) + lane];
        #pragma unroll
        for (int pp = 0; pp < 2; ++pp) {            // rows in pairs: dual chains
          const int rA = 2 * pp, rB = 2 * pp + 1;
          #pragma unroll
          for (int k = 0; k < 4; ++k) {             // exp in place (no extra regs)
            v[rA][k].x = __expf(v[rA][k].x * NEG_INV_EPS);
            v[rA][k].y = __expf(v[rA][k].y * NEG_INV_EPS);
            v[rA][k].z = __expf(v[rA][k].z * NEG_INV_EPS);
            v[rA][k].w = __expf(v[rA][k].w * NEG_INV_EPS);
            v[rB][k].x = __expf(v[rB][k].x * NEG_INV_EPS);
            v[rB][k].y = __expf(v[rB][k].y * NEG_INV_EPS);
            v[rB][k].z = __expf(v[rB][k].z * NEG_INV_EPS);
            v[rB][k].w = __expf(v[rB][k].w * NEG_INV_EPS);
          }
          float dA = 0.f, dB = 0.f;
          #pragma unroll
          for (int k = 0; k < 4; ++k) {
            dA = fmaf(v[rA][k].x, bb[4*k+0], dA);
            dA = fmaf(v[rA][k].y, bb[4*k+1], dA);
            dA = fmaf(v[rA][k].z, bb[4*k+2], dA);
            dA = fmaf(v[rA][k].w, bb[4*k+3], dA);
            dB = fmaf(v[rB][k].x, bb[4*k+0], dB);
            dB = fmaf(v[rB][k].y, bb[4*k+1], dB);
            dB = fmaf(v[rB][k].z, bb[4*k+2], dB);
            dB = fmaf(v[rB][k].w, bb[4*k+3], dB);
          }
          #pragma unroll
          for (int off = 32; off; off >>= 1) {
            dA += __shfl_xor(dA, off);
            dB += __shfl_xor(dB, off);
          }
          const float aA = PAv / fmaxf(dA, 1e-12f);
          const float aB = PAv / fmaxf(dB, 1e-12f);
          #pragma unroll
          for (int k = 0; k < 4; ++k) {
            acc[4*k+0] = fmaf(aA, v[rA][k].x, acc[4*k+0]);
            acc[4*k+1] = fmaf(aA, v[rA][k].y, acc[4*k+1]);
            acc[4*k+2] = fmaf(aA, v[rA][k].z, acc[4*k+2]);
            acc[4*k+3] = fmaf(aA, v[rA][k].w, acc[4*k+3]);
            acc[4*k+0] = fmaf(aB, v[rB][k].x, acc[4*k+0]);
            acc[4*k+1] = fmaf(aB, v[rB][k].y, acc[4*k+1]);
            acc[4*k+2] = fmaf(aB, v[rB][k].z, acc[4*k+2]);
            acc[4*k+3] = fmaf(aB, v[rB][k].w, acc[4*k+3]);
          }
        }
      }
    }

    // block-level column reduction, one atomic per column per block
    if constexpr (BF16) {
      #pragma unroll
      for (int j = 0; j < 8; ++j) {
        wave_cs[wave][8 * lane + j]       = acc[j];
        wave_cs[wave][512 + 8 * lane + j] = acc[8 + j];
      }
    } else {
      #pragma unroll
      for (int k = 0; k < 4; ++k)
        #pragma unroll
        for (int j = 0; j < 4; ++j)
          wave_cs[wave][256 * k + 4 * lane + j] = acc[4 * k + j];
    }
    __syncthreads();
    {
      float s = 0.f;
      #pragma unroll
      for (int w = 0; w < IT_WAVES; ++w) s += wave_cs[w][tid];
      atomicAdd(&cs_cur[tid], s);
    }

    grid.sync();   // the only grid-wide sync per iteration

    // Phase B: every block redundantly (bit-identically) computes b_new + err
    // (ordering identical to round 1, which passed on HW)
    const float c  = cs_cur[tid];
    const float bn = powf(PBv / fmaxf(c, 1e-12f), FI);
    const float e  = bn - b_lds[tid];
    float sq = e * e;
    #pragma unroll
    for (int off = 32; off; off >>= 1) sq += __shfl_xor(sq, off);
    if (lane == 0) redsh[wave] = sq;
    __syncthreads();
    if (tid == 0) {
      float s = 0.f;
      #pragma unroll
      for (int w = 0; w < IT_WAVES; ++w) s += redsh[w];
      err_sh = s;
    }
    b_lds[tid] = bn;     // own-index write; readers blocked by next barrier
    ++it;
    __syncthreads();     // publishes err_sh and b_lds
    if (err_sh <= STOPERR2 || it >= MAXIT) break;
  }

  if (blockIdx.x == 0) b_out[tid] = b_lds[tid];
}

// ---------------- finalize: OT_plan + partial reductions (round-1 proven) ----
constexpr int FN_BLOCKS  = 2048;
constexpr int FN_THREADS = 256;
constexpr int FN_WAVES   = FN_THREADS / 64;                  // 4
constexpr int FN_RPW     = NROWS / (FN_BLOCKS * FN_WAVES);   // 8

__global__ __launch_bounds__(FN_THREADS)
void ssk_finalize_kernel(const float* __restrict__ P, const float* __restrict__ b_glob,
                         float* __restrict__ out, float* __restrict__ wsum,
                         float* __restrict__ loss_part)
{
  __shared__ float b_sh[NK];
  __shared__ float wave_w[FN_WAVES][NK];
  __shared__ float red[FN_WAVES];

  const int tid  = threadIdx.x;
  const int wave = tid >> 6;
  const int lane = tid & 63;

  #pragma unroll
  for (int i = 0; i < 4; ++i) b_sh[tid + 256 * i] = b_glob[tid + 256 * i];
  __syncthreads();

  float bb[16];
  #pragma unroll
  for (int k = 0; k < 4; ++k)
    #pragma unroll
    for (int j = 0; j < 4; ++j)
      bb[4 * k + j] = b_sh[256 * k + 4 * lane + j];

  float wacc[16];
  #pragma unroll
  for (int t = 0; t < 16; ++t) wacc[t] = 0.0f;
  float lacc = 0.0f;

  const int row0 = (blockIdx.x * FN_WAVES + wave) * FN_RPW;
  float4* out4 = reinterpret_cast<float4*>(out);

  for (int r = 0; r < FN_RPW; ++r) {
    const size_t row = (size_t)(row0 + r);
    const float4* rp = reinterpret_cast<const float4*>(P) + row * (NK / 4);
    float4 pv[4];
    float Q[16];
    float dot = 0.0f;
    #pragma unroll
    for (int k = 0; k < 4; ++k) {
      pv[k] = rp[(k << 6) + lane];
      Q[4*k+0] = __expf(pv[k].x * NEG_INV_EPS);
      Q[4*k+1] = __expf(pv[k].y * NEG_INV_EPS);
      Q[4*k+2] = __expf(pv[k].z * NEG_INV_EPS);
      Q[4*k+3] = __expf(pv[k].w * NEG_INV_EPS);
      dot = fmaf(Q[4*k+0], bb[4*k+0], dot);
      dot = fmaf(Q[4*k+1], bb[4*k+1], dot);
      dot = fmaf(Q[4*k+2], bb[4*k+2], dot);
      dot = fmaf(Q[4*k+3], bb[4*k+3], dot);
    }
    #pragma unroll
    for (int off = 32; off; off >>= 1) dot += __shfl_xor(dot, off);
    const float s = 1.0f / fmaxf(dot, 1e-12f);    // N * a_i  (N*Pa = 1)
    #pragma unroll
    for (int k = 0; k < 4; ++k) {
      float4 o;
      o.x = s * Q[4*k+0] * bb[4*k+0];
      o.y = s * Q[4*k+1] * bb[4*k+1];
      o.z = s * Q[4*k+2] * bb[4*k+2];
      o.w = s * Q[4*k+3] * bb[4*k+3];
      out4[row * (NK / 4) + (k << 6) + lane] = o;
      lacc = fmaf(o.x, pv[k].x, lacc);
      lacc = fmaf(o.y, pv[k].y, lacc);
      lacc = fmaf(o.z, pv[k].z, lacc);
      lacc = fmaf(o.w, pv[k].w, lacc);
      wacc[4*k+0] += o.x; wacc[4*k+1] += o.y; wacc[4*k+2] += o.z; wacc[4*k+3] += o.w;
    }
  }

  #pragma unroll
  for (int k = 0; k < 4; ++k)
    #pragma unroll
    for (int j = 0; j < 4; ++j)
      wave_w[wave][256 * k + 4 * lane + j] = wacc[4 * k + j];
  __syncthreads();
  #pragma unroll
  for (int i = 0; i < 4; ++i) {
    const int c = tid + 256 * i;
    float s2 = wave_w[0][c] + wave_w[1][c] + wave_w[2][c] + wave_w[3][c];
    atomicAdd(&wsum[c], s2);
  }

  #pragma unroll
  for (int off = 32; off; off >>= 1) lacc += __shfl_xor(lacc, off);
  if (lane == 0) red[wave] = lacc;
  __syncthreads();
  if (tid == 0) loss_part[blockIdx.x] = red[0] + red[1] + red[2] + red[3];
}

// ---------------- finish: scalars ----------------
__device__ __forceinline__ float ssk_block_sum_1024(float v, float* red, int wave, int lane)
{
  #pragma unroll
  for (int off = 32; off; off >>= 1) v += __shfl_xor(v, off);
  __syncthreads();
  if (lane == 0) red[wave] = v;
  __syncthreads();
  float t = 0.0f;
  #pragma unroll
  for (int w = 0; w < 16; ++w) t += red[w];
  return t;
}

__global__ __launch_bounds__(1024)
void ssk_finish_kernel(const float* __restrict__ wsum, const float* __restrict__ loss_part,
                       float* __restrict__ out)
{
  __shared__ float red[16];
  const int tid = threadIdx.x, wave = tid >> 6, lane = tid & 63;

  float l  = loss_part[tid] + loss_part[tid + 1024];
  float lt = ssk_block_sum_1024(l, red, wave, lane);

  float wm = wsum[tid] * (1.0f / (float)NROWS);
  float sw = ssk_block_sum_1024(wm, red, wave, lane);
  float wn = wm / (sw + 1e-8f);
  float v  = PBv * (logf(PBv) - logf(wn + 1e-7f));
  float rg = ssk_block_sum_1024(v, red, wave, lane);

  if (tid == 0) {
    out[(size_t)NROWS * NK]     = lt / (float)NROWS;  // ot_loss
    out[(size_t)NROWS * NK + 1] = rg;                 // reg
  }
}

// ---------------- launch ----------------
extern "C" void kernel_launch(void* const* d_in, const int* in_sizes, int n_in,
                              void* d_out, int out_size, void* d_ws, size_t ws_size,
                              hipStream_t stream)
{
  const float* P = (const float*)d_in[0];
  float* out = (float*)d_out;
  float* ws  = (float*)d_ws;

  float* cs_ring   = ws;             // [4][1024]
  float* b_glob    = ws + 4096;      // [1024]
  float* wsum      = ws + 5120;      // [1024]
  float* loss_part = ws + 6144;      // [2048]
  void*  qbf       = (void*)(ws + 16384);   // 64 KiB offset: bf16 Q cache
  const size_t need = 16384 * sizeof(float) + (size_t)NROWS * NK * 2;

  // zero ring + b_glob + wsum every call (deterministic across graph replays)
  hipMemsetAsync(ws, 0, 6144 * sizeof(float), stream);

  if (ws_size >= need) {
    q_conv_kernel<<<dim3(2048), dim3(256), 0, stream>>>(P, (uint4*)qbf);
    const void* src = qbf;
    void (*fp)(const void*, float*, float*) = ssk_iter<true>;
    void* args[] = { (void*)&src, (void*)&cs_ring, (void*)&b_glob };
    hipLaunchCooperativeKernel((void*)fp, dim3(IT_BLOCKS), dim3(IT_THREADS),
                               args, 0, stream);
  } else {
    const void* src = (const void*)P;
    void (*fp)(const void*, float*, float*) = ssk_iter<false>;
    void* args[] = { (void*)&src, (void*)&cs_ring, (void*)&b_glob };
    hipLaunchCooperativeKernel((void*)fp, dim3(IT_BLOCKS), dim3(IT_THREADS),
                               args, 0, stream);
  }

  ssk_finalize_kernel<<<dim3(FN_BLOCKS), dim3(FN_THREADS), 0, stream>>>(
      P, b_glob, out, wsum, loss_part);
  ssk_finish_kernel<<<dim3(1), dim3(1024), 0, stream>>>(wsum, loss_part, out);
}

// Round 5
// 65309.491 us; speedup vs baseline: 1.7412x; 1.7412x over previous
//
#include <hip/hip_runtime.h>
#include <hip/hip_cooperative_groups.h>

namespace cg = cooperative_groups;

constexpr int   NROWS = 65536;
constexpr int   NK    = 1024;
constexpr float PAv   = 1.0f / 65536.0f;
constexpr float PBv   = 1.0f / 1024.0f;
constexpr float FI    = 1.0f / 1.1f;          // GAMMA/(GAMMA+eps)
constexpr float NEG_INV_EPS = -10.0f;         // -1/eps
constexpr float STOPERR2 = 1e-12f;            // (1e-6)^2 on squared 2-norm
constexpr int   MAXIT = 1000;

// ---------------- cooperative Sinkhorn iteration ----------------
// Geometry: 256 blocks (1/CU — coop launch with >256 blocks was REJECTED on HW
// in rounds 2/3) x 512 threads. __launch_bounds__(512,2) caps VGPR at 256;
// 8 waves x 256 VGPR = 2048 = full CU pool, so residency can never reject the
// launch regardless of what the compiler allocates.
constexpr int IT_BLOCKS  = 256;
constexpr int IT_THREADS = 512;
constexpr int IT_WAVES   = IT_THREADS / 64;                 // 8
constexpr int IT_RPW     = NROWS / (IT_BLOCKS * IT_WAVES);  // 32 rows per wave

__global__ __launch_bounds__(IT_THREADS, 2)
void ssk_iter(const float* __restrict__ P, float* __restrict__ cs_ring,
              float* __restrict__ b_out)
{
  cg::grid_group grid = cg::this_grid();
  __shared__ float b_lds[NK];
  __shared__ float wave_cs[IT_WAVES][NK];   // 32 KiB
  __shared__ float redsh[IT_WAVES];
  __shared__ float err_sh;

  const int tid  = threadIdx.x;
  const int wave = tid >> 6;
  const int lane = tid & 63;
  const int row0 = (blockIdx.x * IT_WAVES + wave) * IT_RPW;

  b_lds[tid] = PBv; b_lds[tid + 512] = PBv;   // b0 = 1/K
  __syncthreads();

  int it = 0;
  for (;;) {
    float* __restrict__ cs_cur = cs_ring + (size_t)(it & 3) * NK;
    {
      // zero the buffer used 2 iters ahead; its last readers/writers (iter
      // it-2) finished before SYNC(it-1), which every block has passed.
      // Redundant zero-writes across blocks store the same value: benign.
      float* z = cs_ring + (size_t)((it + 2) & 3) * NK;
      z[tid] = 0.0f; z[tid + 512] = 0.0f;
    }

    // lane's 16 columns: 256*k + 4*lane + j  (round-1 layout, 0 LDS conflicts)
    float bb[16];
    #pragma unroll
    for (int k = 0; k < 4; ++k)
      #pragma unroll
      for (int j = 0; j < 4; ++j)
        bb[4 * k + j] = b_lds[256 * k + 4 * lane + j];

    float acc[16];
    #pragma unroll
    for (int t = 0; t < 16; ++t) acc[t] = 0.0f;

    for (int r = 0; r < IT_RPW; r += 8) {   // 8-row batch: 32 float4 loads in flight
      float4 v[8][4];
      #pragma unroll
      for (int rr = 0; rr < 8; ++rr) {
        const float4* rp = reinterpret_cast<const float4*>(P)
                         + (size_t)(row0 + r + rr) * (NK / 4);
        #pragma unroll
        for (int k = 0; k < 4; ++k) v[rr][k] = rp[(k << 6) + lane];
      }
      #pragma unroll
      for (int rr = 0; rr < 8; ++rr) {      // exp in place
        #pragma unroll
        for (int k = 0; k < 4; ++k) {
          v[rr][k].x = __expf(v[rr][k].x * NEG_INV_EPS);
          v[rr][k].y = __expf(v[rr][k].y * NEG_INV_EPS);
          v[rr][k].z = __expf(v[rr][k].z * NEG_INV_EPS);
          v[rr][k].w = __expf(v[rr][k].w * NEG_INV_EPS);
        }
      }
      float d[8];
      #pragma unroll
      for (int rr = 0; rr < 8; ++rr) {
        float dd = 0.f;
        #pragma unroll
        for (int k = 0; k < 4; ++k) {
          dd = fmaf(v[rr][k].x, bb[4*k+0], dd);
          dd = fmaf(v[rr][k].y, bb[4*k+1], dd);
          dd = fmaf(v[rr][k].z, bb[4*k+2], dd);
          dd = fmaf(v[rr][k].w, bb[4*k+3], dd);
        }
        d[rr] = dd;
      }
      #pragma unroll
      for (int off = 32; off; off >>= 1) {   // 8 interleaved butterfly chains
        #pragma unroll
        for (int rr = 0; rr < 8; ++rr) d[rr] += __shfl_xor(d[rr], off);
      }
      float aa[8];
      #pragma unroll
      for (int rr = 0; rr < 8; ++rr) aa[rr] = PAv / fmaxf(d[rr], 1e-12f);
      #pragma unroll
      for (int rr = 0; rr < 8; ++rr) {
        #pragma unroll
        for (int k = 0; k < 4; ++k) {
          acc[4*k+0] = fmaf(aa[rr], v[rr][k].x, acc[4*k+0]);
          acc[4*k+1] = fmaf(aa[rr], v[rr][k].y, acc[4*k+1]);
          acc[4*k+2] = fmaf(aa[rr], v[rr][k].z, acc[4*k+2]);
          acc[4*k+3] = fmaf(aa[rr], v[rr][k].w, acc[4*k+3]);
        }
      }
    }

    // block-level column reduction, one atomic per column per block
    #pragma unroll
    for (int k = 0; k < 4; ++k)
      #pragma unroll
      for (int j = 0; j < 4; ++j)
        wave_cs[wave][256 * k + 4 * lane + j] = acc[4 * k + j];
    __syncthreads();
    #pragma unroll
    for (int h = 0; h < 2; ++h) {
      const int c = tid + 512 * h;
      float s = 0.f;
      #pragma unroll
      for (int w = 0; w < IT_WAVES; ++w) s += wave_cs[w][c];
      atomicAdd(&cs_cur[c], s);
    }

    grid.sync();   // the only grid-wide sync per iteration

    // Phase B: every block redundantly (bit-identically) computes b_new + err
    const float c0 = cs_cur[tid], c1 = cs_cur[tid + 512];
    const float bn0 = powf(PBv / fmaxf(c0, 1e-12f), FI);
    const float bn1 = powf(PBv / fmaxf(c1, 1e-12f), FI);
    const float e0 = bn0 - b_lds[tid], e1 = bn1 - b_lds[tid + 512];
    float sq = e0 * e0 + e1 * e1;
    #pragma unroll
    for (int off = 32; off; off >>= 1) sq += __shfl_xor(sq, off);
    if (lane == 0) redsh[wave] = sq;
    __syncthreads();
    if (tid == 0) {
      float s = 0.f;
      #pragma unroll
      for (int w = 0; w < IT_WAVES; ++w) s += redsh[w];
      err_sh = s;
    }
    b_lds[tid] = bn0; b_lds[tid + 512] = bn1;  // own-index write
    ++it;
    __syncthreads();     // publishes err_sh and b_lds
    if (err_sh <= STOPERR2 || it >= MAXIT) break;
  }

  if (blockIdx.x == 0) { b_out[tid] = b_lds[tid]; b_out[tid + 512] = b_lds[tid + 512]; }
}

// ---------------- finalize: OT_plan + partial reductions (proven) ----------
constexpr int FN_BLOCKS  = 2048;
constexpr int FN_THREADS = 256;
constexpr int FN_WAVES   = FN_THREADS / 64;                  // 4
constexpr int FN_RPW     = NROWS / (FN_BLOCKS * FN_WAVES);   // 8

__global__ __launch_bounds__(FN_THREADS)
void ssk_finalize_kernel(const float* __restrict__ P, const float* __restrict__ b_glob,
                         float* __restrict__ out, float* __restrict__ wsum,
                         float* __restrict__ loss_part)
{
  __shared__ float b_sh[NK];
  __shared__ float wave_w[FN_WAVES][NK];
  __shared__ float red[FN_WAVES];

  const int tid  = threadIdx.x;
  const int wave = tid >> 6;
  const int lane = tid & 63;

  #pragma unroll
  for (int i = 0; i < 4; ++i) b_sh[tid + 256 * i] = b_glob[tid + 256 * i];
  __syncthreads();

  float bb[16];
  #pragma unroll
  for (int k = 0; k < 4; ++k)
    #pragma unroll
    for (int j = 0; j < 4; ++j)
      bb[4 * k + j] = b_sh[256 * k + 4 * lane + j];

  float wacc[16];
  #pragma unroll
  for (int t = 0; t < 16; ++t) wacc[t] = 0.0f;
  float lacc = 0.0f;

  const int row0 = (blockIdx.x * FN_WAVES + wave) * FN_RPW;
  float4* out4 = reinterpret_cast<float4*>(out);

  for (int r = 0; r < FN_RPW; ++r) {
    const size_t row = (size_t)(row0 + r);
    const float4* rp = reinterpret_cast<const float4*>(P) + row * (NK / 4);
    float4 pv[4];
    float Q[16];
    float dot = 0.0f;
    #pragma unroll
    for (int k = 0; k < 4; ++k) {
      pv[k] = rp[(k << 6) + lane];
      Q[4*k+0] = __expf(pv[k].x * NEG_INV_EPS);
      Q[4*k+1] = __expf(pv[k].y * NEG_INV_EPS);
      Q[4*k+2] = __expf(pv[k].z * NEG_INV_EPS);
      Q[4*k+3] = __expf(pv[k].w * NEG_INV_EPS);
      dot = fmaf(Q[4*k+0], bb[4*k+0], dot);
      dot = fmaf(Q[4*k+1], bb[4*k+1], dot);
      dot = fmaf(Q[4*k+2], bb[4*k+2], dot);
      dot = fmaf(Q[4*k+3], bb[4*k+3], dot);
    }
    #pragma unroll
    for (int off = 32; off; off >>= 1) dot += __shfl_xor(dot, off);
    const float s = 1.0f / fmaxf(dot, 1e-12f);    // N * a_i  (N*Pa = 1)
    #pragma unroll
    for (int k = 0; k < 4; ++k) {
      float4 o;
      o.x = s * Q[4*k+0] * bb[4*k+0];
      o.y = s * Q[4*k+1] * bb[4*k+1];
      o.z = s * Q[4*k+2] * bb[4*k+2];
      o.w = s * Q[4*k+3] * bb[4*k+3];
      out4[row * (NK / 4) + (k << 6) + lane] = o;
      lacc = fmaf(o.x, pv[k].x, lacc);
      lacc = fmaf(o.y, pv[k].y, lacc);
      lacc = fmaf(o.z, pv[k].z, lacc);
      lacc = fmaf(o.w, pv[k].w, lacc);
      wacc[4*k+0] += o.x; wacc[4*k+1] += o.y; wacc[4*k+2] += o.z; wacc[4*k+3] += o.w;
    }
  }

  #pragma unroll
  for (int k = 0; k < 4; ++k)
    #pragma unroll
    for (int j = 0; j < 4; ++j)
      wave_w[wave][256 * k + 4 * lane + j] = wacc[4 * k + j];
  __syncthreads();
  #pragma unroll
  for (int i = 0; i < 4; ++i) {
    const int c = tid + 256 * i;
    float s2 = wave_w[0][c] + wave_w[1][c] + wave_w[2][c] + wave_w[3][c];
    atomicAdd(&wsum[c], s2);
  }

  #pragma unroll
  for (int off = 32; off; off >>= 1) lacc += __shfl_xor(lacc, off);
  if (lane == 0) red[wave] = lacc;
  __syncthreads();
  if (tid == 0) loss_part[blockIdx.x] = red[0] + red[1] + red[2] + red[3];
}

// ---------------- finish: scalars ----------------
__device__ __forceinline__ float ssk_block_sum_1024(float v, float* red, int wave, int lane)
{
  #pragma unroll
  for (int off = 32; off; off >>= 1) v += __shfl_xor(v, off);
  __syncthreads();
  if (lane == 0) red[wave] = v;
  __syncthreads();
  float t = 0.0f;
  #pragma unroll
  for (int w = 0; w < 16; ++w) t += red[w];
  return t;
}

__global__ __launch_bounds__(1024)
void ssk_finish_kernel(const float* __restrict__ wsum, const float* __restrict__ loss_part,
                       float* __restrict__ out)
{
  __shared__ float red[16];
  const int tid = threadIdx.x, wave = tid >> 6, lane = tid & 63;

  float l  = loss_part[tid] + loss_part[tid + 1024];
  float lt = ssk_block_sum_1024(l, red, wave, lane);

  float wm = wsum[tid] * (1.0f / (float)NROWS);
  float sw = ssk_block_sum_1024(wm, red, wave, lane);
  float wn = wm / (sw + 1e-8f);
  float v  = PBv * (logf(PBv) - logf(wn + 1e-7f));
  float rg = ssk_block_sum_1024(v, red, wave, lane);

  if (tid == 0) {
    out[(size_t)NROWS * NK]     = lt / (float)NROWS;  // ot_loss
    out[(size_t)NROWS * NK + 1] = rg;                 // reg
  }
}

// ---------------- launch ----------------
extern "C" void kernel_launch(void* const* d_in, const int* in_sizes, int n_in,
                              void* d_out, int out_size, void* d_ws, size_t ws_size,
                              hipStream_t stream)
{
  const float* P = (const float*)d_in[0];
  float* out = (float*)d_out;
  float* ws  = (float*)d_ws;

  float* cs_ring   = ws;             // [4][1024]
  float* b_glob    = ws + 4096;      // [1024]
  float* wsum      = ws + 5120;      // [1024]
  float* loss_part = ws + 6144;      // [2048]

  // zero ring + b_glob + wsum every call (deterministic across graph replays)
  hipMemsetAsync(ws, 0, 6144 * sizeof(float), stream);

  void* args[] = { (void*)&P, (void*)&cs_ring, (void*)&b_glob };
  hipLaunchCooperativeKernel((void*)ssk_iter, dim3(IT_BLOCKS), dim3(IT_THREADS),
                             args, 0, stream);

  ssk_finalize_kernel<<<dim3(FN_BLOCKS), dim3(FN_THREADS), 0, stream>>>(
      P, b_glob, out, wsum, loss_part);
  ssk_finish_kernel<<<dim3(1), dim3(1024), 0, stream>>>(wsum, loss_part, out);
}